// Round 6
// baseline (70.623 us; speedup 1.0000x reference)
//
#include <hip/hip_runtime.h>
#include <hip/hip_bf16.h>

// ContrastiveLoss fused kernel for MI355X (gfx950).
//
// Math reduction (T=0.5):
//   f = x / max(||x||, 1e-8)   (rows)
//   s_ij = f_i . f_j
//   den_i = sum_{j: label_j != label_i} exp(2 s_ij)
//   loss  = sum_i [ c_i * log(den_i) - sum_{j same label, j != i} 2 s_ij ]
//           / (sum_i c_i + 1e-5),   c_i = count(label_i) - 1
//
// N=4096, D=512, labels in [0,100).
//
// Round 6: occupancy push. Round-5 k2 (~26 us) was 2 blocks/CU, capped by
// the 64 KB LDS double-buffer; both floors (MFMA 8.3 us, LDS-BW 7.8 us)
// need more resident waves to overlap the 2-phase barrier drains.
// Changes: 16-row B slabs (2 x 16 KB dbuf, ~33 KB/block -> LDS allows 4),
// __launch_bounds__(256,3) + register slimming (u8-packed labels, folded
// index math) -> 3 blocks/CU / 12 waves. k3 split: k3a (16 blocks,
// per-block LDS hist + partials -> global atomicAdd) + tiny k3b.

typedef short short8 __attribute__((ext_vector_type(8)));
typedef float floatx4 __attribute__((ext_vector_type(4)));
typedef unsigned short u16;
typedef unsigned int u32;
typedef unsigned char u8;

#define N_ROWS 4096
#define DIM 512
#define GRPB 16384             // bytes per 16-row fragment group (16*1024)
#define EPS_NORM 1e-8f
#define EPS_DEN 1e-5f
#define BI 128                 // i-rows per block (4 waves x 32)
#define NBLK_I (N_ROWS / BI)   // 32
#define JSPAN 128              // j-cols per block
#define NJT (JSPAN / 16)       // 8 slabs of 16 rows

static __device__ inline u16 f32_to_bf16(float f) {
  u32 u = __float_as_uint(f);
  u32 r = (u + 0x7FFFu + ((u >> 16) & 1u)) >> 16;   // RNE
  return (u16)r;
}

static __device__ inline void load_lds16(const char* g, char* l) {
  __builtin_amdgcn_global_load_lds(
      (const __attribute__((address_space(1))) void*)g,
      (__attribute__((address_space(3))) void*)l, 16, 0, 0);
}

// wave-per-row normalize + bf16 pack, fragment-major store; grid 1024 x 256.
// G layout: group g = row>>4 (16 rows), chunk kt = k>>5 (32 elems), inside a
// 1 KB chunk lane l = kg*16 + (row&15) holds bytes [l*16, l*16+16) =
// elems k = kt*32 + kg*8 .. +8 of its row (the MFMA A/B fragment map).
__global__ void k1_normalize(const float* __restrict__ x,
                             const int* __restrict__ labels,
                             u16* __restrict__ G, u8* __restrict__ lab8,
                             float* __restrict__ den, float* __restrict__ pos,
                             float* __restrict__ acc2) {
  const int row = blockIdx.x * 4 + (threadIdx.x >> 6);
  const int lane = threadIdx.x & 63;
  const float4* src = reinterpret_cast<const float4*>(x + (size_t)row * DIM);
  float4 v0 = src[lane * 2];
  float4 v1 = src[lane * 2 + 1];
  float ss = v0.x*v0.x + v0.y*v0.y + v0.z*v0.z + v0.w*v0.w
           + v1.x*v1.x + v1.y*v1.y + v1.z*v1.z + v1.w*v1.w;
#pragma unroll
  for (int m = 1; m < 64; m <<= 1) ss += __shfl_xor(ss, m, 64);
  float scale = 1.f / fmaxf(sqrtf(ss), EPS_NORM);
  uint4 o;
  o.x = ((u32)f32_to_bf16(v0.y * scale) << 16) | (u32)f32_to_bf16(v0.x * scale);
  o.y = ((u32)f32_to_bf16(v0.w * scale) << 16) | (u32)f32_to_bf16(v0.z * scale);
  o.z = ((u32)f32_to_bf16(v1.y * scale) << 16) | (u32)f32_to_bf16(v1.x * scale);
  o.w = ((u32)f32_to_bf16(v1.w * scale) << 16) | (u32)f32_to_bf16(v1.z * scale);
  char* dst = (char*)G + (size_t)(row >> 4) * GRPB + (lane >> 2) * 1024
            + ((lane & 3) * 16 + (row & 15)) * 16;
  *reinterpret_cast<uint4*>(dst) = o;
  if (lane == 0) { den[row] = 0.f; pos[row] = 0.f; }
  if (lane == 1) lab8[row] = (u8)labels[row];
  if (blockIdx.x == 0 && threadIdx.x == 0) { acc2[0] = 0.f; acc2[1] = 0.f; }
}

// fused sim-GEMM + per-row reduction.
__global__ __launch_bounds__(256, 3) void k2_fused(
    const u16* __restrict__ G, const u8* __restrict__ lab8,
    float* __restrict__ den, float* __restrict__ pos) {
  // fragment-major B: 2 buffers x 16 chunks (kt) x 1 KB
  __shared__ u16 Bsh[2 * 16 * 512];
  __shared__ int labj_sh[JSPAN];

  const char* Gb = (const char*)G;
  char* bshb = (char*)Bsh;

  const int bid = blockIdx.x;
  const int itile = bid & (NBLK_I - 1);
  const int jch = bid >> 5;               // 32 j-chunks
  const int tid = threadIdx.x;
  const int wv = tid >> 6;
  const int lane = tid & 63;
  const int l15 = lane & 15;
  const int kg = lane >> 4;               // 0..3

  const int ib = itile * BI;
  const int jbase = jch * JSPAN;

  // stage one 16-row B slab (1 fragment group, 16 KB) as 16 chunks; wave wv
  // stages chunks wv*4 .. wv*4+3. Source AND dest contiguous 1 KB (lane*16).
#define STAGE(bufsel, grow) do {                                            \
    _Pragma("unroll")                                                       \
    for (int i_ = 0; i_ < 4; ++i_) {                                        \
      const int c_ = wv * 4 + i_;                                           \
      load_lds16(Gb + (size_t)((grow) >> 4) * GRPB + c_ * 1024 + lane * 16, \
                 bshb + (bufsel) * 16384 + c_ * 1024 + lane * 16);          \
    }                                                                       \
  } while (0)

  // prologue: stage slab 0 into buf 0, labels into LDS
  STAGE(0, jbase);
  if (tid < JSPAN) labj_sh[tid] = lab8[jbase + tid];

  // A fragments: 32 rows/wave = 2 fragment groups, K=512, register-resident.
  short8 a[2][16];
#pragma unroll
  for (int s = 0; s < 2; ++s) {
    const char* abase = Gb + (size_t)((ib >> 4) + wv * 2 + s) * GRPB + lane * 16;
#pragma unroll
    for (int kt = 0; kt < 16; ++kt)
      a[s][kt] = *reinterpret_cast<const short8*>(abase + kt * 1024);
  }
  // pin A in VGPRs (round-1 pathology: compiler sank loads into the loop)
#pragma unroll
  for (int s = 0; s < 2; ++s)
#pragma unroll
    for (int kt = 0; kt < 16; ++kt)
      asm volatile("" : "+v"(a[s][kt]));

  // C/D layout (verified gfx950): col = lane&15 (j), row = kg*4 + r (i).
  // This lane's 8 output rows: i = i_base + s*16 + r, labels packed as u8x4.
  const int i_base = ib + wv * 32 + kg * 4;
  u32 labp0 = *reinterpret_cast<const u32*>(lab8 + i_base);        // s=0, r=0..3
  u32 labp1 = *reinterpret_cast<const u32*>(lab8 + i_base + 16);   // s=1

  float den_acc[2][4] = {{0.f,0.f,0.f,0.f},{0.f,0.f,0.f,0.f}};
  float pos_acc[2][4] = {{0.f,0.f,0.f,0.f},{0.f,0.f,0.f,0.f}};

  __syncthreads();   // buf0 staged, labels ready

  for (int jt = 0; jt < NJT; ++jt) {
    const int cur = jt & 1;
    if (jt + 1 < NJT) STAGE(cur ^ 1, jbase + (jt + 1) * 16);

    const int labj = labj_sh[jt * 16 + l15];
    // diag detect: jrow - i_base == s*16 + r  (r in 0..3)
    const int d = (jbase + jt * 16 + l15) - i_base;

    floatx4 acc0 = {0.f,0.f,0.f,0.f};
    floatx4 acc1 = {0.f,0.f,0.f,0.f};
    const char* bbase = bshb + cur * 16384 + lane * 16;
#pragma unroll
    for (int kt = 0; kt < 16; ++kt) {
      short8 b = *reinterpret_cast<const short8*>(bbase + kt * 1024);
      acc0 = __builtin_amdgcn_mfma_f32_16x16x32_bf16(a[0][kt], b, acc0, 0, 0, 0);
      acc1 = __builtin_amdgcn_mfma_f32_16x16x32_bf16(a[1][kt], b, acc1, 0, 0, 0);
    }

#pragma unroll
    for (int s = 0; s < 2; ++s) {
      const u32 labp = s ? labp1 : labp0;
#pragma unroll
      for (int r = 0; r < 4; ++r) {
        float sv = s ? acc1[r] : acc0[r];
        float s2 = 2.f * sv;
        float e = __expf(s2);
        bool same = ((int)((labp >> (8 * r)) & 255u) == labj);
        den_acc[s][r] += same ? 0.f : e;
        pos_acc[s][r] += (same && (d != s * 16 + r)) ? s2 : 0.f;
      }
    }
    __syncthreads();   // staging for jt+1 done; safe to flip buffers
  }

  // reduce across the 16 cols (lanes with same kg), one atomic per row
#pragma unroll
  for (int s = 0; s < 2; ++s)
#pragma unroll
    for (int r = 0; r < 4; ++r) {
      float dd = den_acc[s][r], p = pos_acc[s][r];
#pragma unroll
      for (int m = 1; m < 16; m <<= 1) {
        dd += __shfl_xor(dd, m, 64);
        p += __shfl_xor(p, m, 64);
      }
      if (l15 == 0) {
        atomicAdd(&den[i_base + s * 16 + r], dd);
        atomicAdd(&pos[i_base + s * 16 + r], p);
      }
    }
#undef STAGE
}

// per-row finalize, 16 blocks x 256 threads; block partial -> global atomics
__global__ void k3a(const float* __restrict__ den, const float* __restrict__ pos,
                    const int* __restrict__ labels, float* __restrict__ acc2) {
  __shared__ int hist[128];
  __shared__ float sn[4], sz[4];
  const int tid = threadIdx.x;
  if (tid < 128) hist[tid] = 0;
  __syncthreads();
  for (int i = tid; i < N_ROWS; i += 256) atomicAdd(&hist[labels[i]], 1);
  __syncthreads();

  const int row = blockIdx.x * 256 + tid;
  int c = hist[labels[row]] - 1;
  float num = (float)c * logf(den[row]) - pos[row];
  float nnz = (float)c;
#pragma unroll
  for (int m = 1; m < 64; m <<= 1) {
    num += __shfl_xor(num, m, 64);
    nnz += __shfl_xor(nnz, m, 64);
  }
  if ((tid & 63) == 0) { sn[tid >> 6] = num; sz[tid >> 6] = nnz; }
  __syncthreads();
  if (tid == 0) {
    atomicAdd(&acc2[0], sn[0] + sn[1] + sn[2] + sn[3]);
    atomicAdd(&acc2[1], sz[0] + sz[1] + sz[2] + sz[3]);
  }
}

__global__ void k3b(const float* __restrict__ acc2, float* __restrict__ out) {
  out[0] = acc2[0] / (acc2[1] + EPS_DEN);
}

extern "C" void kernel_launch(void* const* d_in, const int* in_sizes, int n_in,
                              void* d_out, int out_size, void* d_ws, size_t ws_size,
                              hipStream_t stream) {
  const float* x = (const float*)d_in[0];
  const int* labels = (const int*)d_in[1];

  // ws: G (4MB) | den f32[4096] | pos f32[4096] | lab8 u8[4096] | acc2 f32[2]
  u16* G = (u16*)d_ws;
  float* den = (float*)((char*)d_ws + (size_t)N_ROWS * DIM * 2);
  float* pos = den + N_ROWS;
  u8* lab8 = (u8*)(pos + N_ROWS);
  float* acc2 = (float*)(lab8 + N_ROWS);
  float* out = (float*)d_out;

  hipLaunchKernelGGL(k1_normalize, dim3(N_ROWS / 4), dim3(256), 0, stream,
                     x, labels, G, lab8, den, pos, acc2);
  hipLaunchKernelGGL(k2_fused, dim3(NBLK_I * (N_ROWS / JSPAN)), dim3(256), 0, stream,
                     G, lab8, den, pos);
  hipLaunchKernelGGL(k3a, dim3(16), dim3(256), 0, stream,
                     den, pos, labels, acc2);
  hipLaunchKernelGGL(k3b, dim3(1), dim3(1), 0, stream, acc2, out);
}

// Round 7
// 42.670 us; speedup vs baseline: 1.6551x; 1.6551x over previous
//
#include <hip/hip_runtime.h>
#include <hip/hip_bf16.h>

// ContrastiveLoss fused kernel for MI355X (gfx950).
//
// Math reduction (T=0.5):
//   f = x / max(||x||, 1e-8)   (rows)
//   s_ij = f_i . f_j
//   den_i = sum_{j: label_j != label_i} exp(2 s_ij)
//   loss  = sum_i [ c_i * log(den_i) - sum_{j same label, j != i} 2 s_ij ]
//           / (sum_i c_i + 1e-5),   c_i = count(label_i) - 1
//
// N=4096, D=512, labels in [0,100).
//
// Round 7: occupancy via smaller per-wave footprint (round-6 lesson:
// __launch_bounds__(256,3) capped arch VGPR at 84 < the 128 the pinned A
// needs -> scratch spill, WRITE_SIZE 105 MB, k2 60 us). Now: 16 i-rows
// per wave (A = 64 VGPR), block = 64 i-rows x JSPAN 256, grid 1024
// (= 4 blocks/CU), 16-row dbuf slabs (33 KB LDS -> LDS allows 4/CU),
// natural ~110 total regs -> 4 waves/SIMD with no allocator coercion.
// Two 8-deep MFMA chains per jt for ILP.

typedef short short8 __attribute__((ext_vector_type(8)));
typedef float floatx4 __attribute__((ext_vector_type(4)));
typedef unsigned short u16;
typedef unsigned int u32;
typedef unsigned char u8;

#define N_ROWS 4096
#define DIM 512
#define GRPB 16384             // bytes per 16-row fragment group (16*1024)
#define EPS_NORM 1e-8f
#define EPS_DEN 1e-5f
#define BI 64                  // i-rows per block (4 waves x 16)
#define NBLK_I (N_ROWS / BI)   // 64
#define JSPAN 256              // j-cols per block
#define NJT (JSPAN / 16)       // 16 slabs of 16 rows

static __device__ inline u16 f32_to_bf16(float f) {
  u32 u = __float_as_uint(f);
  u32 r = (u + 0x7FFFu + ((u >> 16) & 1u)) >> 16;   // RNE
  return (u16)r;
}

static __device__ inline void load_lds16(const char* g, char* l) {
  __builtin_amdgcn_global_load_lds(
      (const __attribute__((address_space(1))) void*)g,
      (__attribute__((address_space(3))) void*)l, 16, 0, 0);
}

// wave-per-row normalize + bf16 pack, fragment-major store; grid 1024 x 256.
// G layout: group g = row>>4 (16 rows), chunk kt = k>>5 (32 elems), inside a
// 1 KB chunk lane l = kg*16 + (row&15) holds bytes [l*16, l*16+16) =
// elems k = kt*32 + kg*8 .. +8 of its row (the MFMA A/B fragment map).
__global__ void k1_normalize(const float* __restrict__ x,
                             const int* __restrict__ labels,
                             u16* __restrict__ G, u8* __restrict__ lab8,
                             float* __restrict__ den, float* __restrict__ pos,
                             float* __restrict__ acc2) {
  const int row = blockIdx.x * 4 + (threadIdx.x >> 6);
  const int lane = threadIdx.x & 63;
  const float4* src = reinterpret_cast<const float4*>(x + (size_t)row * DIM);
  float4 v0 = src[lane * 2];
  float4 v1 = src[lane * 2 + 1];
  float ss = v0.x*v0.x + v0.y*v0.y + v0.z*v0.z + v0.w*v0.w
           + v1.x*v1.x + v1.y*v1.y + v1.z*v1.z + v1.w*v1.w;
#pragma unroll
  for (int m = 1; m < 64; m <<= 1) ss += __shfl_xor(ss, m, 64);
  float scale = 1.f / fmaxf(sqrtf(ss), EPS_NORM);
  uint4 o;
  o.x = ((u32)f32_to_bf16(v0.y * scale) << 16) | (u32)f32_to_bf16(v0.x * scale);
  o.y = ((u32)f32_to_bf16(v0.w * scale) << 16) | (u32)f32_to_bf16(v0.z * scale);
  o.z = ((u32)f32_to_bf16(v1.y * scale) << 16) | (u32)f32_to_bf16(v1.x * scale);
  o.w = ((u32)f32_to_bf16(v1.w * scale) << 16) | (u32)f32_to_bf16(v1.z * scale);
  char* dst = (char*)G + (size_t)(row >> 4) * GRPB + (lane >> 2) * 1024
            + ((lane & 3) * 16 + (row & 15)) * 16;
  *reinterpret_cast<uint4*>(dst) = o;
  if (lane == 0) { den[row] = 0.f; pos[row] = 0.f; }
  if (lane == 1) lab8[row] = (u8)labels[row];
  if (blockIdx.x == 0 && threadIdx.x == 0) { acc2[0] = 0.f; acc2[1] = 0.f; }
}

// fused sim-GEMM + per-row reduction.
__global__ __launch_bounds__(256, 2) void k2_fused(
    const u16* __restrict__ G, const u8* __restrict__ lab8,
    float* __restrict__ den, float* __restrict__ pos) {
  // fragment-major B: 2 buffers x 16 chunks (kt) x 1 KB
  __shared__ u16 Bsh[2 * 16 * 512];
  __shared__ int labj_sh[JSPAN];

  const char* Gb = (const char*)G;
  char* bshb = (char*)Bsh;

  const int bid = blockIdx.x;
  const int itile = bid & (NBLK_I - 1);
  const int jch = bid >> 6;               // 16 j-chunks
  const int tid = threadIdx.x;
  const int wv = tid >> 6;
  const int lane = tid & 63;
  const int l15 = lane & 15;
  const int kg = lane >> 4;               // 0..3

  const int jbase = jch * JSPAN;

  // stage one 16-row B slab (1 fragment group, 16 KB) as 16 chunks; wave wv
  // stages chunks wv*4 .. wv*4+3. Source AND dest contiguous 1 KB (lane*16).
#define STAGE(bufsel, grow) do {                                            \
    _Pragma("unroll")                                                       \
    for (int i_ = 0; i_ < 4; ++i_) {                                        \
      const int c_ = wv * 4 + i_;                                           \
      load_lds16(Gb + (size_t)((grow) >> 4) * GRPB + c_ * 1024 + lane * 16, \
                 bshb + (bufsel) * 16384 + c_ * 1024 + lane * 16);          \
    }                                                                       \
  } while (0)

  // prologue: stage slab 0 into buf 0, labels into LDS
  STAGE(0, jbase);
  labj_sh[tid] = lab8[jbase + tid];

  // A fragments: 16 rows/wave = 1 fragment group, K=512, register-resident.
  short8 a[16];
  {
    const char* abase = Gb + (size_t)(itile * 4 + wv) * GRPB + lane * 16;
#pragma unroll
    for (int kt = 0; kt < 16; ++kt)
      a[kt] = *reinterpret_cast<const short8*>(abase + kt * 1024);
  }
  // pin A in VGPRs (round-1 pathology: compiler sank loads into the loop)
#pragma unroll
  for (int kt = 0; kt < 16; ++kt)
    asm volatile("" : "+v"(a[kt]));

  // C/D layout (verified gfx950): col = lane&15 (j), row = kg*4 + r (i).
  // This lane's 4 output rows: i = i_base + r, labels packed as u8x4.
  const int i_base = itile * BI + wv * 16 + kg * 4;
  const u32 labp = *reinterpret_cast<const u32*>(lab8 + i_base);

  float den_acc[4] = {0.f, 0.f, 0.f, 0.f};
  float pos_acc[4] = {0.f, 0.f, 0.f, 0.f};

  __syncthreads();   // buf0 staged, labels ready

  for (int jt = 0; jt < NJT; ++jt) {
    const int cur = jt & 1;
    if (jt + 1 < NJT) STAGE(cur ^ 1, jbase + (jt + 1) * 16);

    const int labj = labj_sh[jt * 16 + l15];
    // diag detect: jrow - i_base == r  (r in 0..3)
    const int d = (jbase + jt * 16 + l15) - i_base;

    // two 8-deep MFMA chains for ILP
    floatx4 acc_a = {0.f, 0.f, 0.f, 0.f};
    floatx4 acc_b = {0.f, 0.f, 0.f, 0.f};
    const char* bbase = bshb + cur * 16384 + lane * 16;
#pragma unroll
    for (int kt = 0; kt < 8; ++kt) {
      short8 b0 = *reinterpret_cast<const short8*>(bbase + kt * 1024);
      short8 b1 = *reinterpret_cast<const short8*>(bbase + (kt + 8) * 1024);
      acc_a = __builtin_amdgcn_mfma_f32_16x16x32_bf16(a[kt], b0, acc_a, 0, 0, 0);
      acc_b = __builtin_amdgcn_mfma_f32_16x16x32_bf16(a[kt + 8], b1, acc_b, 0, 0, 0);
    }

#pragma unroll
    for (int r = 0; r < 4; ++r) {
      float s2 = 2.f * (acc_a[r] + acc_b[r]);
      float e = __expf(s2);
      bool same = ((int)((labp >> (8 * r)) & 255u) == labj);
      den_acc[r] += same ? 0.f : e;
      pos_acc[r] += (same && (d != r)) ? s2 : 0.f;
    }
    __syncthreads();   // staging for jt+1 done; safe to flip buffers
  }

  // reduce across the 16 cols (lanes with same kg), one atomic per row
#pragma unroll
  for (int r = 0; r < 4; ++r) {
    float dd = den_acc[r], p = pos_acc[r];
#pragma unroll
    for (int m = 1; m < 16; m <<= 1) {
      dd += __shfl_xor(dd, m, 64);
      p += __shfl_xor(p, m, 64);
    }
    if (l15 == 0) {
      atomicAdd(&den[i_base + r], dd);
      atomicAdd(&pos[i_base + r], p);
    }
  }
#undef STAGE
}

// per-row finalize, 16 blocks x 256 threads; block partial -> global atomics
__global__ void k3a(const float* __restrict__ den, const float* __restrict__ pos,
                    const int* __restrict__ labels, float* __restrict__ acc2) {
  __shared__ int hist[128];
  __shared__ float sn[4], sz[4];
  const int tid = threadIdx.x;
  if (tid < 128) hist[tid] = 0;
  __syncthreads();
  for (int i = tid; i < N_ROWS; i += 256) atomicAdd(&hist[labels[i]], 1);
  __syncthreads();

  const int row = blockIdx.x * 256 + tid;
  int c = hist[labels[row]] - 1;
  float num = (float)c * logf(den[row]) - pos[row];
  float nnz = (float)c;
#pragma unroll
  for (int m = 1; m < 64; m <<= 1) {
    num += __shfl_xor(num, m, 64);
    nnz += __shfl_xor(nnz, m, 64);
  }
  if ((tid & 63) == 0) { sn[tid >> 6] = num; sz[tid >> 6] = nnz; }
  __syncthreads();
  if (tid == 0) {
    atomicAdd(&acc2[0], sn[0] + sn[1] + sn[2] + sn[3]);
    atomicAdd(&acc2[1], sz[0] + sz[1] + sz[2] + sz[3]);
  }
}

__global__ void k3b(const float* __restrict__ acc2, float* __restrict__ out) {
  out[0] = acc2[0] / (acc2[1] + EPS_DEN);
}

extern "C" void kernel_launch(void* const* d_in, const int* in_sizes, int n_in,
                              void* d_out, int out_size, void* d_ws, size_t ws_size,
                              hipStream_t stream) {
  const float* x = (const float*)d_in[0];
  const int* labels = (const int*)d_in[1];

  // ws: G (4MB) | den f32[4096] | pos f32[4096] | lab8 u8[4096] | acc2 f32[2]
  u16* G = (u16*)d_ws;
  float* den = (float*)((char*)d_ws + (size_t)N_ROWS * DIM * 2);
  float* pos = den + N_ROWS;
  u8* lab8 = (u8*)(pos + N_ROWS);
  float* acc2 = (float*)(lab8 + N_ROWS);
  float* out = (float*)d_out;

  hipLaunchKernelGGL(k1_normalize, dim3(N_ROWS / 4), dim3(256), 0, stream,
                     x, labels, G, lab8, den, pos, acc2);
  hipLaunchKernelGGL(k2_fused, dim3(NBLK_I * (N_ROWS / JSPAN)), dim3(256), 0, stream,
                     G, lab8, den, pos);
  hipLaunchKernelGGL(k3a, dim3(16), dim3(256), 0, stream,
                     den, pos, labels, acc2);
  hipLaunchKernelGGL(k3b, dim3(1), dim3(1), 0, stream, acc2, out);
}